// Round 2
// baseline (132.738 us; speedup 1.0000x reference)
//
#include <hip/hip_runtime.h>
#include <stdint.h>

// Problem constants (fixed by setup_inputs).
#define N_LIDAR   8192
#define M_QUERIES 32768   // 1024 rays * 32 samples
#define D_FEAT    128
#define SEG_LEN   512
#define N_SEG     (N_LIDAR / SEG_LEN)      // 16
#define Q_PER_THREAD 2
#define BLOCK     256
#define Q_PER_BLOCK (BLOCK * Q_PER_THREAD) // 512
#define N_QTILES  (M_QUERIES / Q_PER_BLOCK) // 64

// Workspace: [0, M_QUERIES*8) : u64 argmin keys (memset to 0xFF each launch).

// Fused argmin: each block stages one lidar segment into LDS, computing
// (-2lx,-2ly,-2lz, ks) on the fly. Scaling by -2 is exact in f32 (power of
// two), and commutes with rounding through every mul/add, so
//   c' = (qx*(-2lx) + qy*(-2ly)) + qz*(-2lz)  ==  -2 * [(m0+m1)+m2]  bit-exact
//   d2 = (qs + c') + ks                       ==  fl(fl(qs-2c)+ks)   bit-exact
// which matches the numpy reference's rounding order exactly.
// grid = (64 qtiles, 16 segs) = 1024 blocks = 4 blocks/CU -> 16 waves/CU.
__global__ __launch_bounds__(BLOCK, 4)
void argmin_kernel(const float* __restrict__ pts,
                   const float* __restrict__ lidar,
                   unsigned long long* __restrict__ keys) {
    #pragma clang fp contract(off)
    __shared__ float4 lds[SEG_LEN];
    const int tid   = threadIdx.x;
    const int qtile = blockIdx.x;
    const int seg   = blockIdx.y;
    const int base  = seg * SEG_LEN;

    // Stage + transform this segment's candidates (lidar is L2-resident).
    for (int k = tid; k < SEG_LEN; k += BLOCK) {
        float lx = lidar[3 * (base + k) + 0];
        float ly = lidar[3 * (base + k) + 1];
        float lz = lidar[3 * (base + k) + 2];
        // Match np.sum(k*k, -1) rounding: (lx^2 + ly^2) + lz^2, no FMA.
        float ks = (lx * lx + ly * ly) + lz * lz;
        lds[k] = make_float4(-2.0f * lx, -2.0f * ly, -2.0f * lz, ks);
    }

    float qx[Q_PER_THREAD], qy[Q_PER_THREAD], qz[Q_PER_THREAD], qs[Q_PER_THREAD];
    float bd[Q_PER_THREAD];
    int   bi[Q_PER_THREAD];
    #pragma unroll
    for (int qq = 0; qq < Q_PER_THREAD; ++qq) {
        int m = qtile * Q_PER_BLOCK + qq * BLOCK + tid;
        float x = pts[3 * m + 0];
        float y = pts[3 * m + 1];
        float z = pts[3 * m + 2];
        qx[qq] = x; qy[qq] = y; qz[qq] = z;
        // Match np.sum(q*q, -1) rounding: (x^2 + y^2) + z^2, no FMA.
        qs[qq] = (x * x + y * y) + z * z;
        bd[qq] = __builtin_inff();
        bi[qq] = 0;
    }
    __syncthreads();

    // Inner scan: broadcast LDS read (all lanes same address -> conflict-free).
    // Strict < keeps FIRST min (np.argmin first-occurrence).
    #pragma unroll 4
    for (int j = 0; j < SEG_LEN; ++j) {
        float4 p = lds[j];
        #pragma unroll
        for (int qq = 0; qq < Q_PER_THREAD; ++qq) {
            float c  = (qx[qq] * p.x + qy[qq] * p.y) + qz[qq] * p.z; // = -2*cross, exact
            float t  = qs[qq] + c;            // = fl(qs - 2*cross)
            float d2 = t + p.w;               // = fl(t + ks)
            bool lt = d2 < bd[qq];
            bd[qq] = lt ? d2 : bd[qq];
            bi[qq] = lt ? j  : bi[qq];
        }
    }

    // Combine across segments via monotone u64 key: smaller d2 wins, ties ->
    // smaller global index (matches np.argmin first-occurrence semantics).
    #pragma unroll
    for (int qq = 0; qq < Q_PER_THREAD; ++qq) {
        int m = qtile * Q_PER_BLOCK + qq * BLOCK + tid;
        unsigned int u = __float_as_uint(bd[qq]);
        u ^= (u >> 31) ? 0xFFFFFFFFu : 0x80000000u;  // order-preserving flip
        unsigned long long key =
            ((unsigned long long)u << 13) |
            (unsigned long long)(base + bi[qq]);
        atomicMin(&keys[m], key);
    }
}

// Gather 128 f32 features per query (32 lanes * float4 per query).
__global__ __launch_bounds__(BLOCK)
void gather_kernel(const unsigned long long* __restrict__ keys,
                   const float4* __restrict__ feat,
                   float4* __restrict__ out) {
    int t    = blockIdx.x * blockDim.x + threadIdx.x;
    int q    = t >> 5;         // 32 lanes per query
    int lane = t & 31;
    unsigned long long key = keys[q];
    int idx = (int)(key & (unsigned long long)(N_LIDAR - 1));
    out[q * (D_FEAT / 4) + lane] = feat[idx * (D_FEAT / 4) + lane];
}

extern "C" void kernel_launch(void* const* d_in, const int* in_sizes, int n_in,
                              void* d_out, int out_size, void* d_ws, size_t ws_size,
                              hipStream_t stream) {
    const float* pts      = (const float*)d_in[0];   // (1,1024,32,3)
    const float* lidar    = (const float*)d_in[1];   // (1,8192,3)
    const float* features = (const float*)d_in[2];   // (1,8192,128)
    float* out = (float*)d_out;                      // (1,1024,32,128)

    unsigned long long* keys = (unsigned long long*)d_ws;

    // Init keys to all-ones (0xFF... = +inf key). Memset node is graph-safe.
    hipMemsetAsync(keys, 0xFF, M_QUERIES * sizeof(unsigned long long), stream);
    argmin_kernel<<<dim3(N_QTILES, N_SEG), BLOCK, 0, stream>>>(pts, lidar, keys);
    gather_kernel<<<(M_QUERIES * 32) / BLOCK, BLOCK, 0, stream>>>(
        keys, (const float4*)features, (float4*)out);
}